// Round 6
// baseline (274.012 us; speedup 1.0000x reference)
//
#include <hip/hip_runtime.h>
#include <hip/hip_cooperative_groups.h>
#include <math.h>

namespace cg = cooperative_groups;

// MinkowskiInstanceNorm fused: segment instance-norm, N x C=32, S segments (sorted seg_ids).
// ws layout (floats): SUM[64*32] @0, SUMSQ @2048, CNT[64] @4096.

#define WS_SUM   0
#define WS_SUMSQ 2048
#define WS_CNT   4096

typedef float f32x4 __attribute__((ext_vector_type(4)));

__global__ void zero_ws_kernel(float* __restrict__ ws) {
    int t = blockIdx.x * blockDim.x + threadIdx.x;
    if (t < 4160) ws[t] = 0.0f;   // SUM + SUMSQ + CNT
}

#define ACC4(A, Q, V)                                        \
    do {                                                     \
        (A).x += (V).x; (A).y += (V).y;                      \
        (A).z += (V).z; (A).w += (V).w;                      \
        (Q).x += (V).x * (V).x; (Q).y += (V).y * (V).y;      \
        (Q).z += (V).z * (V).z; (Q).w += (V).w * (V).w;      \
    } while (0)

#define ADD4(A, B)                                           \
    do {                                                     \
        (A).x += (B).x; (A).y += (B).y;                      \
        (A).z += (B).z; (A).w += (B).w;                      \
    } while (0)

// ---- Phase A body, shared by fused & fallback (device function) ----
__device__ __forceinline__ void reduce_chunk(
        const float4* __restrict__ feats4, const int* __restrict__ seg,
        float* __restrict__ sum_g, float* __restrict__ sumsq_g,
        float* __restrict__ cnt_g,
        float4* s_sum, float4* s_sq, int* s_c,
        int t, int cg_i, int rl,
        int bstart, int bend, int rows, int seg_first, int seg_last) {
    if (seg_first == seg_last) {
        // fast path: single segment, 8 independent load streams
        float4 a0 = make_float4(0.f,0.f,0.f,0.f), a1 = a0, a2 = a0, a3 = a0;
        float4 q0 = a0, q1 = a0, q2 = a0, q3 = a0;
        const float4* p = feats4 + (size_t)(bstart + rl) * 8 + cg_i;
        int r = rl;
        for (; r + 224 < rows; r += 256) {     // 8 rows-of-32 per iter
            float4 v0 = p[0 * 256];
            float4 v1 = p[1 * 256];
            float4 v2 = p[2 * 256];
            float4 v3 = p[3 * 256];
            float4 v4 = p[4 * 256];
            float4 v5 = p[5 * 256];
            float4 v6 = p[6 * 256];
            float4 v7 = p[7 * 256];
            ACC4(a0, q0, v0);
            ACC4(a1, q1, v1);
            ACC4(a2, q2, v2);
            ACC4(a3, q3, v3);
            ACC4(a0, q0, v4);
            ACC4(a1, q1, v5);
            ACC4(a2, q2, v6);
            ACC4(a3, q3, v7);
            p += 8 * 256;
        }
        for (; r < rows; r += 32) {
            float4 v = *p;
            ACC4(a0, q0, v);
            p += 256;
        }
        ADD4(a0, a1); ADD4(a2, a3); ADD4(a0, a2);
        ADD4(q0, q1); ADD4(q2, q3); ADD4(q0, q2);
        s_sum[t] = a0;
        s_sq[t]  = q0;
        __syncthreads();
        for (int off = 128; off >= 8; off >>= 1) {
            if (t < off) {
                float4 a = s_sum[t + off], bb = s_sq[t + off];
                ADD4(s_sum[t], a);
                ADD4(s_sq[t], bb);
            }
            __syncthreads();
        }
        if (t < 8) {
            float4 a = s_sum[t], bb = s_sq[t];
            int base = seg_first * 32 + t * 4;
            atomicAdd(&sum_g[base + 0], a.x);
            atomicAdd(&sum_g[base + 1], a.y);
            atomicAdd(&sum_g[base + 2], a.z);
            atomicAdd(&sum_g[base + 3], a.w);
            atomicAdd(&sumsq_g[base + 0], bb.x);
            atomicAdd(&sumsq_g[base + 1], bb.y);
            atomicAdd(&sumsq_g[base + 2], bb.z);
            atomicAdd(&sumsq_g[base + 3], bb.w);
        }
        if (t == 0) atomicAdd(&cnt_g[seg_first], (float)rows);
    } else {
        // general path: block straddles segment boundary (rare)
        for (int s = seg_first; s <= seg_last; ++s) {
            float4 acc  = make_float4(0.f, 0.f, 0.f, 0.f);
            float4 accq = make_float4(0.f, 0.f, 0.f, 0.f);
            int c = 0;
            for (int r = bstart + rl; r < bend; r += 32) {
                if (seg[r] == s) {
                    float4 v = feats4[(size_t)r * 8 + cg_i];
                    ACC4(acc, accq, v);
                    c++;
                }
            }
            s_sum[t] = acc;
            s_sq[t]  = accq;
            s_c[t]   = (cg_i == 0) ? c : 0;
            __syncthreads();
            for (int off = 128; off >= 8; off >>= 1) {
                if (t < off) {
                    float4 a = s_sum[t + off], bb = s_sq[t + off];
                    ADD4(s_sum[t], a);
                    ADD4(s_sq[t], bb);
                    s_c[t] += s_c[t + off];
                }
                __syncthreads();
            }
            if (t < 8) {
                float4 a = s_sum[t], bb = s_sq[t];
                int base = s * 32 + t * 4;
                atomicAdd(&sum_g[base + 0], a.x);
                atomicAdd(&sum_g[base + 1], a.y);
                atomicAdd(&sum_g[base + 2], a.z);
                atomicAdd(&sum_g[base + 3], a.w);
                atomicAdd(&sumsq_g[base + 0], bb.x);
                atomicAdd(&sumsq_g[base + 1], bb.y);
                atomicAdd(&sumsq_g[base + 2], bb.z);
                atomicAdd(&sumsq_g[base + 3], bb.w);
            }
            if (t == 0) {
                int ctot = s_c[0] + s_c[1] + s_c[2] + s_c[3]
                         + s_c[4] + s_c[5] + s_c[6] + s_c[7];
                atomicAdd(&cnt_g[s], (float)ctot);
            }
            __syncthreads();
        }
    }
}

// 512 blocks x 256 threads; 2 blocks/CU needed, LDS 25.6KB (6/CU possible).
__global__ __launch_bounds__(256, 2) void fused_kernel(
        const float4* __restrict__ feats4, const int* __restrict__ seg,
        const float* __restrict__ w, const float* __restrict__ b,
        const int* __restrict__ nsp, float* __restrict__ ws,
        float* __restrict__ out, int N, int chunk) {
    __shared__ float4 s_sum[256];
    __shared__ float4 s_sq[256];
    __shared__ int    s_c[256];
    __shared__ float  s_scale[2048];   // up to 64 segments x 32 ch
    __shared__ float  s_shift[2048];

    float* sum_g   = ws + WS_SUM;
    float* sumsq_g = ws + WS_SUMSQ;
    float* cnt_g   = ws + WS_CNT;

    int t  = threadIdx.x;
    int cg_i = t & 7;
    int rl = t >> 3;
    int bstart = blockIdx.x * chunk;
    int bend   = min(N, bstart + chunk);
    bool active = bstart < N;
    int rows = active ? (bend - bstart) : 0;
    int seg_first = 0, seg_last = 0;

    if (active) {
        seg_first = seg[bstart];
        seg_last  = seg[bend - 1];
        reduce_chunk(feats4, seg, sum_g, sumsq_g, cnt_g,
                     s_sum, s_sq, s_c, t, cg_i, rl,
                     bstart, bend, rows, seg_first, seg_last);
    }

    cg::this_grid().sync();

    // stats: scale/shift into LDS (every block computes all S*32)
    int ns = *nsp;
    int tot = min(ns, 64) * 32;
    for (int i = t; i < tot; i += 256) {
        int c = i & 31;
        int s = i >> 5;
        float cnt  = fmaxf(cnt_g[s], 1.0f);
        float mean = sum_g[i] / cnt;
        float var  = fmaxf(sumsq_g[i] / cnt - mean * mean, 0.0f);
        float inv  = rsqrtf(var + 1e-8f);
        float sc   = inv * w[c];
        s_scale[i] = sc;
        s_shift[i] = b[c] - mean * sc;
    }
    __syncthreads();

    // Phase B: apply over own (cache-hot) chunk
    if (active) {
        const f32x4* sc4 = (const f32x4*)s_scale;
        const f32x4* sh4 = (const f32x4*)s_shift;
        const f32x4* f4  = (const f32x4*)feats4;
        f32x4*       o4  = (f32x4*)out;

        if (seg_first == seg_last) {
            f32x4 sc = sc4[seg_first * 8 + cg_i];
            f32x4 sh = sh4[seg_first * 8 + cg_i];
            int r = rl;
            size_t idx = (size_t)(bstart + rl) * 8 + cg_i;
            for (; r + 96 < rows; r += 128, idx += 1024) {
                f32x4 v0 = f4[idx +   0];
                f32x4 v1 = f4[idx + 256];
                f32x4 v2 = f4[idx + 512];
                f32x4 v3 = f4[idx + 768];
                f32x4 o0, o1, o2, o3;
                o0.x = fmaf(v0.x, sc.x, sh.x); o0.y = fmaf(v0.y, sc.y, sh.y);
                o0.z = fmaf(v0.z, sc.z, sh.z); o0.w = fmaf(v0.w, sc.w, sh.w);
                o1.x = fmaf(v1.x, sc.x, sh.x); o1.y = fmaf(v1.y, sc.y, sh.y);
                o1.z = fmaf(v1.z, sc.z, sh.z); o1.w = fmaf(v1.w, sc.w, sh.w);
                o2.x = fmaf(v2.x, sc.x, sh.x); o2.y = fmaf(v2.y, sc.y, sh.y);
                o2.z = fmaf(v2.z, sc.z, sh.z); o2.w = fmaf(v2.w, sc.w, sh.w);
                o3.x = fmaf(v3.x, sc.x, sh.x); o3.y = fmaf(v3.y, sc.y, sh.y);
                o3.z = fmaf(v3.z, sc.z, sh.z); o3.w = fmaf(v3.w, sc.w, sh.w);
                __builtin_nontemporal_store(o0, &o4[idx +   0]);
                __builtin_nontemporal_store(o1, &o4[idx + 256]);
                __builtin_nontemporal_store(o2, &o4[idx + 512]);
                __builtin_nontemporal_store(o3, &o4[idx + 768]);
            }
            for (; r < rows; r += 32, idx += 256) {
                f32x4 v = f4[idx];
                f32x4 o;
                o.x = fmaf(v.x, sc.x, sh.x); o.y = fmaf(v.y, sc.y, sh.y);
                o.z = fmaf(v.z, sc.z, sh.z); o.w = fmaf(v.w, sc.w, sh.w);
                __builtin_nontemporal_store(o, &o4[idx]);
            }
        } else {
            for (int r = bstart + rl; r < bend; r += 32) {
                int s = seg[r];
                size_t idx = (size_t)r * 8 + cg_i;
                f32x4 v  = f4[idx];
                f32x4 sc = sc4[s * 8 + cg_i];
                f32x4 sh = sh4[s * 8 + cg_i];
                f32x4 o;
                o.x = fmaf(v.x, sc.x, sh.x); o.y = fmaf(v.y, sc.y, sh.y);
                o.z = fmaf(v.z, sc.z, sh.z); o.w = fmaf(v.w, sc.w, sh.w);
                __builtin_nontemporal_store(o, &o4[idx]);
            }
        }
    }
}

// ---------------- fallback (non-cooperative) path ----------------
__global__ __launch_bounds__(256) void reduce_kernel(
        const float4* __restrict__ feats4, const int* __restrict__ seg,
        float* __restrict__ ws, int N, int chunk) {
    __shared__ float4 s_sum[256];
    __shared__ float4 s_sq[256];
    __shared__ int    s_c[256];
    int t  = threadIdx.x;
    int bstart = blockIdx.x * chunk;
    if (bstart >= N) return;
    int bend = min(N, bstart + chunk);
    reduce_chunk(feats4, seg, ws + WS_SUM, ws + WS_SUMSQ, ws + WS_CNT,
                 s_sum, s_sq, s_c, t, t & 7, t >> 3,
                 bstart, bend, bend - bstart, seg[bstart], seg[bend - 1]);
}

__global__ void stats_kernel(const float* __restrict__ w,
                             const float* __restrict__ b,
                             const int* __restrict__ nsp,
                             float* __restrict__ ws) {
    const float* sum_g   = ws + WS_SUM;
    const float* sumsq_g = ws + WS_SUMSQ;
    const float* cnt_g   = ws + WS_CNT;
    float* scale_g = ws + WS_CNT + 64;          // SCALE @4160
    float* shift_g = ws + WS_CNT + 64 + 2048;   // SHIFT @6208
    int t  = threadIdx.x;
    int ns = *nsp;
    for (int i = t; i < ns * 32; i += blockDim.x) {
        int s = i >> 5, c = i & 31;
        float cnt  = fmaxf(cnt_g[s], 1.0f);
        float mean = sum_g[i] / cnt;
        float var  = fmaxf(sumsq_g[i] / cnt - mean * mean, 0.0f);
        float inv  = rsqrtf(var + 1e-8f);
        float sc   = inv * w[c];
        scale_g[i] = sc;
        shift_g[i] = b[c] - mean * sc;
    }
}

__global__ __launch_bounds__(256) void apply_kernel(
        const float* __restrict__ feats, const int* __restrict__ seg,
        const float* __restrict__ ws, float* __restrict__ out, int total4) {
    const f32x4* f4 = (const f32x4*)feats;
    f32x4*       o4 = (f32x4*)out;
    const f32x4* scale4 = (const f32x4*)(ws + WS_CNT + 64);
    const f32x4* shift4 = (const f32x4*)(ws + WS_CNT + 64 + 2048);
    int stride = gridDim.x * blockDim.x;
    for (int i = blockIdx.x * blockDim.x + threadIdx.x; i < total4; i += stride) {
        int row = i >> 3, cg = i & 7;
        int s = seg[row];
        f32x4 v  = f4[i];
        f32x4 sc = scale4[s * 8 + cg];
        f32x4 sh = shift4[s * 8 + cg];
        f32x4 o;
        o.x = fmaf(v.x, sc.x, sh.x); o.y = fmaf(v.y, sc.y, sh.y);
        o.z = fmaf(v.z, sc.z, sh.z); o.w = fmaf(v.w, sc.w, sh.w);
        __builtin_nontemporal_store(o, &o4[i]);
    }
}

extern "C" void kernel_launch(void* const* d_in, const int* in_sizes, int n_in,
                              void* d_out, int out_size, void* d_ws, size_t ws_size,
                              hipStream_t stream) {
    const float* feats = (const float*)d_in[0];
    const int*   seg   = (const int*)d_in[1];
    const float* w     = (const float*)d_in[2];
    const float* b     = (const float*)d_in[3];
    const int*   nsp   = (const int*)d_in[4];
    float* out = (float*)d_out;
    float* ws  = (float*)d_ws;

    int N = in_sizes[1];
    int total4 = N * 8;

    hipLaunchKernelGGL(zero_ws_kernel, dim3(17), dim3(256), 0, stream, ws);

    const int NB = 512;                 // 2 blocks/CU co-residency, wide margin
    int chunk = (N + NB - 1) / NB;
    const float4* feats4 = (const float4*)feats;
    void* args[] = { (void*)&feats4, (void*)&seg, (void*)&w, (void*)&b,
                     (void*)&nsp, (void*)&ws, (void*)&out, (void*)&N, (void*)&chunk };
    hipError_t err = hipLaunchCooperativeKernel((void*)fused_kernel, dim3(NB),
                                                dim3(256), args, 0, stream);
    if (err != hipSuccess) {
        // deterministic fallback: proven 3-kernel path
        (void)hipGetLastError();
        const int NB2 = 2048;
        int chunk2 = (N + NB2 - 1) / NB2;
        hipLaunchKernelGGL(reduce_kernel, dim3(NB2), dim3(256), 0, stream,
                           feats4, seg, ws, N, chunk2);
        hipLaunchKernelGGL(stats_kernel, dim3(1), dim3(256), 0, stream,
                           w, b, nsp, ws);
        hipLaunchKernelGGL(apply_kernel, dim3(4096), dim3(256), 0, stream,
                           feats, seg, ws, out, total4);
    }
}

// Round 7
// 188.521 us; speedup vs baseline: 1.4535x; 1.4535x over previous
//
#include <hip/hip_runtime.h>
#include <math.h>

// MinkowskiInstanceNorm: segment instance-norm, N x C=32, S<=64 segments (sorted seg_ids).
// ws (floats): SUM[64*32]@0, SUMSQ@2048, CNT[64]@4096, SCALE@4160, SHIFT@6208.

#define WS_SUM   0
#define WS_SUMSQ 2048
#define WS_CNT   4096
#define WS_SCALE 4160
#define WS_SHIFT 6208

typedef float f32x4 __attribute__((ext_vector_type(4)));

__global__ void zero_ws_kernel(float* __restrict__ ws) {
    int t = blockIdx.x * blockDim.x + threadIdx.x;
    if (t < 4160) ws[t] = 0.0f;   // SUM + SUMSQ + CNT
}

// Streaming reduce, apply-shaped: block owns 4096 consecutive float4 (=512 rows),
// thread t handles i = blk*4096 + k*256 + t for k=0..15 (stride 32 rows).
// cg = t&7 is the thread's fixed channel-group (i&7 == t&7).
__global__ __launch_bounds__(256) void reduce_kernel(
        const f32x4* __restrict__ f4, const int* __restrict__ seg,
        float* __restrict__ ws, int total4, int N) {
    __shared__ float s_sum[2048];   // 64 segs x 32 ch
    __shared__ float s_sq[2048];
    __shared__ float s_cnt[64];
    int t = threadIdx.x;
    for (int j = t; j < 2048; j += 256) { s_sum[j] = 0.0f; s_sq[j] = 0.0f; }
    if (t < 64) s_cnt[t] = 0.0f;
    __syncthreads();

    int cg = t & 7;
    int i0 = blockIdx.x * 4096 + t;
    int row_first = (blockIdx.x * 4096) >> 3;
    int row_last  = min(row_first + 511, N - 1);

    if (row_first < N) {
        int sA = seg[row_first];
        int sB = seg[row_last];

        f32x4 acc  = {0.f, 0.f, 0.f, 0.f};
        f32x4 accq = {0.f, 0.f, 0.f, 0.f};

        if (sA == sB) {
            // fast path: whole block in one segment, branch-free short loop
            float rcnt = 0.0f;
            #pragma unroll
            for (int k = 0; k < 16; ++k) {
                int i = i0 + k * 256;
                if (i < total4) {
                    f32x4 v = f4[i];
                    acc  += v;
                    accq += v * v;
                    rcnt += 1.0f;
                }
            }
            int bse = sA * 32 + cg * 4;
            atomicAdd(&s_sum[bse + 0], acc.x);
            atomicAdd(&s_sum[bse + 1], acc.y);
            atomicAdd(&s_sum[bse + 2], acc.z);
            atomicAdd(&s_sum[bse + 3], acc.w);
            atomicAdd(&s_sq[bse + 0], accq.x);
            atomicAdd(&s_sq[bse + 1], accq.y);
            atomicAdd(&s_sq[bse + 2], accq.z);
            atomicAdd(&s_sq[bse + 3], accq.w);
            if (cg == 0) atomicAdd(&s_cnt[sA], rcnt);
        } else {
            // slow path (<=7 blocks): per-iteration segment tracking
            int cur = -1;
            float rcnt = 0.0f;
            for (int k = 0; k < 16; ++k) {
                int i = i0 + k * 256;
                if (i >= total4) break;
                int s = seg[i >> 3];
                if (s != cur) {
                    if (cur >= 0) {
                        int bse = cur * 32 + cg * 4;
                        atomicAdd(&s_sum[bse + 0], acc.x);
                        atomicAdd(&s_sum[bse + 1], acc.y);
                        atomicAdd(&s_sum[bse + 2], acc.z);
                        atomicAdd(&s_sum[bse + 3], acc.w);
                        atomicAdd(&s_sq[bse + 0], accq.x);
                        atomicAdd(&s_sq[bse + 1], accq.y);
                        atomicAdd(&s_sq[bse + 2], accq.z);
                        atomicAdd(&s_sq[bse + 3], accq.w);
                        if (cg == 0) atomicAdd(&s_cnt[cur], rcnt);
                    }
                    acc = (f32x4){0.f, 0.f, 0.f, 0.f};
                    accq = (f32x4){0.f, 0.f, 0.f, 0.f};
                    rcnt = 0.0f;
                    cur = s;
                }
                f32x4 v = f4[i];
                acc  += v;
                accq += v * v;
                rcnt += 1.0f;
            }
            if (cur >= 0) {
                int bse = cur * 32 + cg * 4;
                atomicAdd(&s_sum[bse + 0], acc.x);
                atomicAdd(&s_sum[bse + 1], acc.y);
                atomicAdd(&s_sum[bse + 2], acc.z);
                atomicAdd(&s_sum[bse + 3], acc.w);
                atomicAdd(&s_sq[bse + 0], accq.x);
                atomicAdd(&s_sq[bse + 1], accq.y);
                atomicAdd(&s_sq[bse + 2], accq.z);
                atomicAdd(&s_sq[bse + 3], accq.w);
                if (cg == 0) atomicAdd(&s_cnt[cur], rcnt);
            }
        }
    }
    __syncthreads();

    // block -> global, skip zero bins (segments this block never touched)
    for (int j = t; j < 2048; j += 256) {
        float v1 = s_sum[j];
        float v2 = s_sq[j];
        if (v1 != 0.0f) atomicAdd(&ws[WS_SUM + j], v1);
        if (v2 != 0.0f) atomicAdd(&ws[WS_SUMSQ + j], v2);
    }
    if (t < 64) {
        float c = s_cnt[t];
        if (c != 0.0f) atomicAdd(&ws[WS_CNT + t], c);
    }
}

__global__ void stats_kernel(const float* __restrict__ w,
                             const float* __restrict__ b,
                             const int* __restrict__ nsp,
                             float* __restrict__ ws) {
    const float* sum_g   = ws + WS_SUM;
    const float* sumsq_g = ws + WS_SUMSQ;
    const float* cnt_g   = ws + WS_CNT;
    float* scale_g = ws + WS_SCALE;
    float* shift_g = ws + WS_SHIFT;
    int t  = threadIdx.x;
    int ns = min(*nsp, 64);
    for (int i = t; i < ns * 32; i += blockDim.x) {
        int s = i >> 5, c = i & 31;
        float cnt  = fmaxf(cnt_g[s], 1.0f);
        float mean = sum_g[i] / cnt;
        float var  = fmaxf(sumsq_g[i] / cnt - mean * mean, 0.0f);
        float inv  = rsqrtf(var + 1e-8f);
        float sc   = inv * w[c];
        scale_g[i] = sc;
        shift_g[i] = b[c] - mean * sc;
    }
}

__global__ __launch_bounds__(256) void apply_kernel(
        const float* __restrict__ feats, const int* __restrict__ seg,
        const float* __restrict__ ws, float* __restrict__ out, int total4) {
    const f32x4* f4 = (const f32x4*)feats;
    f32x4*       o4 = (f32x4*)out;
    const f32x4* scale4 = (const f32x4*)(ws + WS_SCALE);
    const f32x4* shift4 = (const f32x4*)(ws + WS_SHIFT);
    int stride = gridDim.x * blockDim.x;
    for (int i = blockIdx.x * blockDim.x + threadIdx.x; i < total4; i += stride) {
        int row = i >> 3, cg = i & 7;
        int s = seg[row];
        f32x4 v  = __builtin_nontemporal_load(&f4[i]);
        f32x4 sc = scale4[s * 8 + cg];
        f32x4 sh = shift4[s * 8 + cg];
        f32x4 o;
        o.x = fmaf(v.x, sc.x, sh.x); o.y = fmaf(v.y, sc.y, sh.y);
        o.z = fmaf(v.z, sc.z, sh.z); o.w = fmaf(v.w, sc.w, sh.w);
        __builtin_nontemporal_store(o, &o4[i]);
    }
}

extern "C" void kernel_launch(void* const* d_in, const int* in_sizes, int n_in,
                              void* d_out, int out_size, void* d_ws, size_t ws_size,
                              hipStream_t stream) {
    const float* feats = (const float*)d_in[0];
    const int*   seg   = (const int*)d_in[1];
    const float* w     = (const float*)d_in[2];
    const float* b     = (const float*)d_in[3];
    const int*   nsp   = (const int*)d_in[4];
    float* out = (float*)d_out;
    float* ws  = (float*)d_ws;

    int N = in_sizes[1];
    int total4 = N * 8;
    int nblk = (total4 + 4095) / 4096;

    hipLaunchKernelGGL(zero_ws_kernel, dim3(17), dim3(256), 0, stream, ws);
    hipLaunchKernelGGL(reduce_kernel, dim3(nblk), dim3(256), 0, stream,
                       (const f32x4*)feats, seg, ws, total4, N);
    hipLaunchKernelGGL(stats_kernel, dim3(1), dim3(256), 0, stream,
                       w, b, nsp, ws);
    hipLaunchKernelGGL(apply_kernel, dim3(4096), dim3(256), 0, stream,
                       feats, seg, ws, out, total4);
}